// Round 1
// baseline (252075.244 us; speedup 1.0000x reference)
//
#include <hip/hip_runtime.h>
#include <math.h>

#define NDATA   20000
#define DFEAT   1024
#define TWO_M   64
#define MM      32
#define ETA_F   1e-4f
#define THRES_F 1e-12f
#define KB      8          // steps per batch
#define NSWEEP  12         // Jacobi sweeps (deterministic, converged for f32 at ~8)

// s_big is reused: alpha batch alds[8][1024]  OR  shrink tile[256][65] (pad 65: bank-friendly)
#define TILE(r,c) s_big[(r)*65 + (c)]

__device__ __forceinline__ void pair_from(int p, int &a, int &b) {
    // p in [0, 2080) -> (a,b) with a<=b over 64x64 upper triangle
    int a_ = 0, rem = p;
    while (rem >= 64 - a_) { rem -= 64 - a_; ++a_; }
    a = a_; b = a_ + rem;
}

__global__ __launch_bounds__(1024)
void SFTRL_CCFM_kernel(const float* __restrict__ A,   // [20000][1024]
                       const float* __restrict__ Y,   // [20000]
                       float* __restrict__ out)       // [20000]
{
    const int tid = threadIdx.x;
    const int j   = tid >> 4;     // column 0..63
    const int s   = tid & 15;     // row-slice 0..15
    const int wv  = tid >> 6;     // wave 0..15
    const int ln  = tid & 63;     // lane in wave

    __shared__ float s_big[16640];        // 66.6 KB (alds / tile union)
    __shared__ float s_G[2][4096];        // 32 KB  (Jacobi G double-buffer; [0] reused as Ueff)
    __shared__ float s_U[2][4096];        // 32 KB  (Jacobi U double-buffer)
    __shared__ float s_pm[KB * 64];
    __shared__ float s_sraw[KB];
    __shared__ float s_corr[KB];
    __shared__ float s_bv[KB];
    __shared__ float s_red[16];
    __shared__ float s_rotA[64];
    __shared__ float s_rotB[64];
    __shared__ int   s_prt[64];
    __shared__ float s_S[64];
    __shared__ float s_Ss[64];
    __shared__ int   s_perm[64];
    __shared__ int   s_misc[2];           // [0]=nnz [1]=ge

    // B in registers: thread (j,s) holds B[4s+64m+i][j] in bf4[m] component i
    float4 bf4[16];
#pragma unroll
    for (int m = 0; m < 16; ++m) bf4[m] = make_float4(0.f, 0.f, 0.f, 0.f);

    int rc = 0;
    int t  = 0;

    while (t < NDATA) {
        int bsz = NDATA - t; if (bsz > KB) bsz = KB;

        __syncthreads();                       // protect s_big reuse
        // stage alpha rows (float4 granularity): s_big[k*1024 + r]
        for (int i = tid; i < bsz * 256; i += 1024)
            ((float4*)s_big)[i] = ((const float4*)(A + (size_t)t * DFEAT))[i];
        if (tid < bsz) s_bv[tid]   = Y[t + tid];
        if (tid < KB)  s_corr[tid] = 0.f;
        __syncthreads();

        // P[k][j] = alpha_k . B[:,j]  (partial over this thread's 64 rows)
        float p[KB];
#pragma unroll
        for (int k = 0; k < KB; ++k) p[k] = 0.f;
#pragma unroll
        for (int m = 0; m < 16; ++m) {
            const int base = s + 16 * m;
#pragma unroll
            for (int k = 0; k < KB; ++k) {
                float4 a = ((const float4*)s_big)[k * 256 + base];
                p[k] += bf4[m].x * a.x + bf4[m].y * a.y + bf4[m].z * a.z + bf4[m].w * a.w;
            }
        }
        // reduce over the 16 s-slices (consecutive lanes)
#pragma unroll
        for (int k = 0; k < KB; ++k) {
            p[k] += __shfl_xor(p[k], 1);
            p[k] += __shfl_xor(p[k], 2);
            p[k] += __shfl_xor(p[k], 4);
            p[k] += __shfl_xor(p[k], 8);
        }
        if (s == 0) {
#pragma unroll
            for (int k = 0; k < KB; ++k) s_pm[k * 64 + j] = p[k];
        }
        __syncthreads();

        // raw scalars: wave k sums squares of P[k][*]
        if (wv < KB) {
            float v = s_pm[wv * 64 + ln];
            v = v * v;
            v += __shfl_xor(v, 1);  v += __shfl_xor(v, 2);  v += __shfl_xor(v, 4);
            v += __shfl_xor(v, 8);  v += __shfl_xor(v, 16); v += __shfl_xor(v, 32);
            if (ln == 0) s_sraw[wv] = v;
        }
        __syncthreads();

        // ---- sequential trigger pass over the batch (uniform control flow) ----
        bool shrunk = false;
        for (int k = 0; k < bsz; ++k) {
            float sc = s_sraw[k] + s_corr[k];
            if (tid == 0) out[t + k] = sc;
            float b = s_bv[k];
            if (sc <= b) {                         // uniform branch
                rc += 1;
                float kap = sqrtf(2.f * ETA_F * (b - sc));
                if (j == rc) {                     // write new column into registers
#pragma unroll
                    for (int m = 0; m < 16; ++m) {
                        float4 a = ((const float4*)s_big)[k * 256 + s + 16 * m];
                        bf4[m] = make_float4(kap * a.x, kap * a.y, kap * a.z, kap * a.w);
                    }
                }
                if (rc == TWO_M - 1) {
                    // ================= SHRINK (pure LDS, deterministic) =================
                    // S1: Gram G = B^T B via 4 register->LDS tiles of 256 rows
                    float acc0 = 0.f, acc1 = 0.f, acc2 = 0.f;
                    int a0i, b0i, a1i, b1i, a2i, b2i;
                    pair_from(tid,        a0i, b0i);
                    pair_from(tid + 1024, a1i, b1i);
                    pair_from((tid < 32) ? (tid + 2048) : 0, a2i, b2i);
#pragma unroll
                    for (int T = 0; T < 4; ++T) {
                        __syncthreads();
#pragma unroll
                        for (int mm = 0; mm < 4; ++mm) {
                            int rl = 4 * s + 64 * mm;
                            const float4 v = bf4[4 * T + mm];
                            TILE(rl + 0, j) = v.x; TILE(rl + 1, j) = v.y;
                            TILE(rl + 2, j) = v.z; TILE(rl + 3, j) = v.w;
                        }
                        __syncthreads();
                        for (int r = 0; r < 256; ++r) {
                            acc0 += TILE(r, a0i) * TILE(r, b0i);
                            acc1 += TILE(r, a1i) * TILE(r, b1i);
                            acc2 += TILE(r, a2i) * TILE(r, b2i);
                        }
                    }
                    s_G[0][a0i * 64 + b0i] = acc0; s_G[0][b0i * 64 + a0i] = acc0;
                    s_G[0][a1i * 64 + b1i] = acc1; s_G[0][b1i * 64 + a1i] = acc1;
                    if (tid < 32) { s_G[0][a2i * 64 + b2i] = acc2; s_G[0][b2i * 64 + a2i] = acc2; }
#pragma unroll
                    for (int e4 = 0; e4 < 4; ++e4) {
                        int e = tid + e4 * 1024;
                        s_U[0][e] = ((e >> 6) == (e & 63)) ? 1.f : 0.f;
                    }
                    __syncthreads();

                    // S2: tournament-cyclic Jacobi, double-buffered, 2 barriers/round
                    int cur = 0;
                    for (int sw = 0; sw < NSWEEP; ++sw) {
                        for (int r = 0; r < 63; ++r) {
                            if (tid < 32) {
                                int p_, q_;
                                if (tid == 0) { p_ = 63; q_ = r; }
                                else { p_ = (r + tid) % 63; q_ = (r + 63 - tid) % 63; }
                                float gpp = s_G[cur][p_ * 64 + p_];
                                float gqq = s_G[cur][q_ * 64 + q_];
                                float gpq = s_G[cur][p_ * 64 + q_];
                                float c = 1.f, sn = 0.f;
                                if (fabsf(gpq) > 1e-20f) {
                                    float tau = (gqq - gpp) / (2.f * gpq);
                                    float tt  = (tau >= 0.f ? 1.f : -1.f) /
                                                (fabsf(tau) + sqrtf(1.f + tau * tau));
                                    c  = 1.f / sqrtf(1.f + tt * tt);
                                    sn = tt * c;
                                }
                                s_rotA[p_] = c;  s_rotB[p_] = -sn; s_prt[p_] = q_;
                                s_rotA[q_] = c;  s_rotB[q_] = sn;  s_prt[q_] = p_;
                            }
                            __syncthreads();
                            float ng[4], nu[4];
#pragma unroll
                            for (int e4 = 0; e4 < 4; ++e4) {
                                int e   = tid + e4 * 1024;
                                int row = e >> 6, col = e & 63;
                                int pr = s_prt[row], pc = s_prt[col];
                                float ar = s_rotA[row], br = s_rotB[row];
                                float ac = s_rotA[col], bc = s_rotB[col];
                                ng[e4] = ar * ac * s_G[cur][row * 64 + col]
                                       + br * ac * s_G[cur][pr * 64 + col]
                                       + ar * bc * s_G[cur][row * 64 + pc]
                                       + br * bc * s_G[cur][pr * 64 + pc];
                                nu[e4] = ac * s_U[cur][row * 64 + col]
                                       + bc * s_U[cur][row * 64 + pc];
                            }
#pragma unroll
                            for (int e4 = 0; e4 < 4; ++e4) {
                                int e = tid + e4 * 1024;
                                s_G[cur ^ 1][e] = ng[e4];
                                s_U[cur ^ 1][e] = nu[e4];
                            }
                            __syncthreads();
                            cur ^= 1;
                        }
                    }

                    // S3: eigenvalues, threshold, sort descending (stable rank)
                    if (tid < 64) {
                        float lam = s_G[cur][tid * 64 + tid];
                        if (lam <= THRES_F) lam = 0.f;
                        s_S[tid] = lam;
                    }
                    __syncthreads();
                    if (tid < 64) {
                        float my = s_S[tid];
                        int rank = 0;
                        for (int i = 0; i < 64; ++i) {
                            float o = s_S[i];
                            rank += ((o > my) || (o == my && i < tid)) ? 1 : 0;
                        }
                        s_perm[rank] = tid;
                        s_Ss[rank]   = my;
                    }
                    __syncthreads();
                    if (tid == 0) {
                        int nz = 0;
                        for (int i = 0; i < 64; ++i) nz += (s_Ss[i] > 0.f) ? 1 : 0;
                        s_misc[0] = nz;
                        s_misc[1] = (nz >= MM) ? 1 : 0;
                    }
                    __syncthreads();
                    const int   nnz = s_misc[0];
                    const int   ge  = s_misc[1];
                    const float S32 = s_Ss[MM];

                    // S4: Ueff[k][jn] = U[k][perm[jn]] * net_scale(jn)   (into s_G[0])
#pragma unroll
                    for (int e4 = 0; e4 < 4; ++e4) {
                        int e = tid + e4 * 1024;
                        int kk = e >> 6, jn = e & 63;
                        float Sj = s_Ss[jn];
                        float f;
                        if (ge) f = (jn < MM - 1 && Sj > 0.f)
                                      ? sqrtf(fmaxf(Sj - S32, 0.f) / Sj) : 0.f;
                        else    f = (jn < nnz) ? 1.f : 0.f;
                        s_G[0][kk * 64 + jn] = s_U[cur][kk * 64 + s_perm[jn]] * f;
                    }
                    __syncthreads();

                    // S5: remix B <- B * Ueff, tile by tile (old rows staged to LDS first)
#pragma unroll
                    for (int T = 0; T < 4; ++T) {
                        __syncthreads();
#pragma unroll
                        for (int mm = 0; mm < 4; ++mm) {
                            int rl = 4 * s + 64 * mm;
                            const float4 v = bf4[4 * T + mm];
                            TILE(rl + 0, j) = v.x; TILE(rl + 1, j) = v.y;
                            TILE(rl + 2, j) = v.z; TILE(rl + 3, j) = v.w;
                        }
                        __syncthreads();
#pragma unroll
                        for (int mm = 0; mm < 4; ++mm) {
                            int rl = 4 * s + 64 * mm;
                            float n0 = 0.f, n1 = 0.f, n2 = 0.f, n3 = 0.f;
                            for (int kk = 0; kk < 64; ++kk) {
                                float u = s_G[0][kk * 64 + j];
                                n0 += TILE(rl + 0, kk) * u;
                                n1 += TILE(rl + 1, kk) * u;
                                n2 += TILE(rl + 2, kk) * u;
                                n3 += TILE(rl + 3, kk) * u;
                            }
                            bf4[4 * T + mm] = make_float4(n0, n1, n2, n3);
                        }
                    }
                    rc = ge ? (MM - 1) : nnz;
                    // =============== end SHRINK ===============
                    shrunk = true;
                    t = t + k + 1;   // restart batching after the shrink step
                    break;
                }
                // in-batch additive corrections: scalar_{k2} += (kap * (a_k . a_k2))^2
                for (int k2 = k + 1; k2 < bsz; ++k2) {
                    float prod = s_big[k * 1024 + tid] * s_big[k2 * 1024 + tid];
                    prod += __shfl_xor(prod, 1);  prod += __shfl_xor(prod, 2);
                    prod += __shfl_xor(prod, 4);  prod += __shfl_xor(prod, 8);
                    prod += __shfl_xor(prod, 16); prod += __shfl_xor(prod, 32);
                    if (ln == 0) s_red[wv] = prod;
                    __syncthreads();
                    if (tid < 16) {
                        float v2 = s_red[tid];
                        v2 += __shfl_xor(v2, 1); v2 += __shfl_xor(v2, 2);
                        v2 += __shfl_xor(v2, 4); v2 += __shfl_xor(v2, 8);
                        if (tid == 0) {
                            float g = kap * v2;
                            s_corr[k2] += g * g;
                        }
                    }
                    __syncthreads();
                }
            }
        }
        if (!shrunk) t += bsz;
    }
}

extern "C" void kernel_launch(void* const* d_in, const int* in_sizes, int n_in,
                              void* d_out, int out_size, void* d_ws, size_t ws_size,
                              hipStream_t stream) {
    (void)in_sizes; (void)n_in; (void)d_ws; (void)ws_size; (void)out_size;
    const float* A = (const float*)d_in[0];   // inputs_matrix [20000,1024] f32
    const float* Y = (const float*)d_in[1];   // outputs [20000] f32
    float* out = (float*)d_out;               // preds [20000] f32
    SFTRL_CCFM_kernel<<<dim3(1), dim3(1024), 0, stream>>>(A, Y, out);
}

// Round 2
// 22185.480 us; speedup vs baseline: 11.3622x; 11.3622x over previous
//
#include <hip/hip_runtime.h>
#include <math.h>

#define NDATA   20000
#define DFEAT   1024
#define TWO_M   64
#define MM      32
#define ETA_F   1e-4f
#define THRES_F 1e-12f
#define KB      8          // steps per batch
#define NSWEEP  10         // Jacobi sweeps (cyclic 64x64 converges ~6-8)

// s_big is reused: alpha batch alds[8][1024]  OR  shrink tile[256][65] (pad 65: bank-friendly)
#define TILE(r,c) s_big[(r)*65 + (c)]

__device__ __forceinline__ void pair_from(int p, int &a, int &b) {
    // p in [0, 2080) -> (a,b) with a<=b over 64x64 upper triangle
    int a_ = 0, rem = p;
    while (rem >= 64 - a_) { rem -= 64 - a_; ++a_; }
    a = a_; b = a_ + rem;
}

// 1024 threads = 16 waves = 4 waves/EU; second arg 4 -> VGPR cap ~128/thread (no spill of bf4[16])
__global__ __launch_bounds__(1024, 4)
void SFTRL_CCFM_kernel(const float* __restrict__ A,   // [20000][1024]
                       const float* __restrict__ Y,   // [20000]
                       float* __restrict__ out)       // [20000]
{
    const int tid = threadIdx.x;
    const int j   = tid >> 4;     // column 0..63
    const int s   = tid & 15;     // row-slice 0..15
    const int wv  = tid >> 6;     // wave 0..15
    const int ln  = tid & 63;     // lane in wave

    __shared__ float s_big[16640];        // 66.6 KB (alds / tile union)
    __shared__ float s_G[2][4096];        // 32 KB  (Jacobi G double-buffer; [0] reused as Ueff)
    __shared__ float s_U[2][4096];        // 32 KB  (Jacobi U double-buffer)
    __shared__ float s_pm[KB * 64];
    __shared__ float s_sraw[KB];
    __shared__ float s_corr[KB];
    __shared__ float s_bv[KB];
    __shared__ float s_rotA[64];
    __shared__ float s_rotB[64];
    __shared__ int   s_prt[64];
    __shared__ float s_S[64];
    __shared__ float s_Ss[64];
    __shared__ int   s_perm[64];
    __shared__ int   s_misc[2];           // [0]=nnz [1]=ge

    // B in registers: thread (j,s) holds B[4s+64m+i][j] in bf4[m] component i
    float4 bf4[16];
#pragma unroll
    for (int m = 0; m < 16; ++m) bf4[m] = make_float4(0.f, 0.f, 0.f, 0.f);

    int rc = 0;
    int t  = 0;

    while (t < NDATA) {
        int bsz = NDATA - t; if (bsz > KB) bsz = KB;

        __syncthreads();                       // protect s_big reuse
        // stage alpha rows (float4 granularity): s_big[k*1024 + r]
        for (int i = tid; i < bsz * 256; i += 1024)
            ((float4*)s_big)[i] = ((const float4*)(A + (size_t)t * DFEAT))[i];
        if (tid < bsz) s_bv[tid]   = Y[t + tid];
        if (tid < KB)  s_corr[tid] = 0.f;
        __syncthreads();

        // P[k][j] = alpha_k . B[:,j]  (partial over this thread's 64 rows)
        float p[KB];
#pragma unroll
        for (int k = 0; k < KB; ++k) p[k] = 0.f;
#pragma unroll
        for (int m = 0; m < 16; ++m) {
            const int base = s + 16 * m;
#pragma unroll
            for (int k = 0; k < KB; ++k) {
                float4 a = ((const float4*)s_big)[k * 256 + base];
                p[k] += bf4[m].x * a.x + bf4[m].y * a.y + bf4[m].z * a.z + bf4[m].w * a.w;
            }
        }
        // reduce over the 16 s-slices (consecutive lanes)
#pragma unroll
        for (int k = 0; k < KB; ++k) {
            p[k] += __shfl_xor(p[k], 1);
            p[k] += __shfl_xor(p[k], 2);
            p[k] += __shfl_xor(p[k], 4);
            p[k] += __shfl_xor(p[k], 8);
        }
        if (s == 0) {
#pragma unroll
            for (int k = 0; k < KB; ++k) s_pm[k * 64 + j] = p[k];
        }
        __syncthreads();

        // raw scalars: wave k sums squares of P[k][*]
        if (wv < KB) {
            float v = s_pm[wv * 64 + ln];
            v = v * v;
            v += __shfl_xor(v, 1);  v += __shfl_xor(v, 2);  v += __shfl_xor(v, 4);
            v += __shfl_xor(v, 8);  v += __shfl_xor(v, 16); v += __shfl_xor(v, 32);
            if (ln == 0) s_sraw[wv] = v;
        }
        __syncthreads();

        // ---- sequential trigger pass over the batch (uniform control flow) ----
        bool shrunk = false;
        for (int k = 0; k < bsz; ++k) {
            float sc = s_sraw[k] + s_corr[k];
            if (tid == 0) out[t + k] = sc;
            float b = s_bv[k];
            if (sc <= b) {                         // uniform branch
                rc += 1;
                float kap = sqrtf(2.f * ETA_F * (b - sc));
                if (j == rc) {                     // write new column into registers
#pragma unroll
                    for (int m = 0; m < 16; ++m) {
                        float4 a = ((const float4*)s_big)[k * 256 + s + 16 * m];
                        bf4[m] = make_float4(kap * a.x, kap * a.y, kap * a.z, kap * a.w);
                    }
                }
                if (rc == TWO_M - 1) {
                    // ================= SHRINK (pure LDS, deterministic) =================
                    // S1: Gram G = B^T B via 4 register->LDS tiles of 256 rows
                    float acc0 = 0.f, acc1 = 0.f, acc2 = 0.f;
                    int a0i, b0i, a1i, b1i, a2i, b2i;
                    pair_from(tid,        a0i, b0i);
                    pair_from(tid + 1024, a1i, b1i);
                    pair_from((tid < 32) ? (tid + 2048) : 0, a2i, b2i);
#pragma unroll
                    for (int T = 0; T < 4; ++T) {
                        __syncthreads();
#pragma unroll
                        for (int mm = 0; mm < 4; ++mm) {
                            int rl = 4 * s + 64 * mm;
                            const float4 v = bf4[4 * T + mm];
                            TILE(rl + 0, j) = v.x; TILE(rl + 1, j) = v.y;
                            TILE(rl + 2, j) = v.z; TILE(rl + 3, j) = v.w;
                        }
                        __syncthreads();
                        for (int r = 0; r < 256; ++r) {
                            acc0 += TILE(r, a0i) * TILE(r, b0i);
                            acc1 += TILE(r, a1i) * TILE(r, b1i);
                            acc2 += TILE(r, a2i) * TILE(r, b2i);
                        }
                    }
                    s_G[0][a0i * 64 + b0i] = acc0; s_G[0][b0i * 64 + a0i] = acc0;
                    s_G[0][a1i * 64 + b1i] = acc1; s_G[0][b1i * 64 + a1i] = acc1;
                    if (tid < 32) { s_G[0][a2i * 64 + b2i] = acc2; s_G[0][b2i * 64 + a2i] = acc2; }
#pragma unroll
                    for (int e4 = 0; e4 < 4; ++e4) {
                        int e = tid + e4 * 1024;
                        s_U[0][e] = ((e >> 6) == (e & 63)) ? 1.f : 0.f;
                    }
                    __syncthreads();

                    // S2: tournament-cyclic Jacobi, double-buffered, 2 barriers/round
                    int cur = 0;
                    for (int sw = 0; sw < NSWEEP; ++sw) {
                        for (int r = 0; r < 63; ++r) {
                            if (tid < 32) {
                                int p_, q_;
                                if (tid == 0) { p_ = 63; q_ = r; }
                                else { p_ = (r + tid) % 63; q_ = (r + 63 - tid) % 63; }
                                float gpp = s_G[cur][p_ * 64 + p_];
                                float gqq = s_G[cur][q_ * 64 + q_];
                                float gpq = s_G[cur][p_ * 64 + q_];
                                float c = 1.f, sn = 0.f;
                                if (fabsf(gpq) > 1e-20f) {
                                    float tau = (gqq - gpp) / (2.f * gpq);
                                    float tt  = (tau >= 0.f ? 1.f : -1.f) /
                                                (fabsf(tau) + sqrtf(1.f + tau * tau));
                                    c  = 1.f / sqrtf(1.f + tt * tt);
                                    sn = tt * c;
                                }
                                s_rotA[p_] = c;  s_rotB[p_] = -sn; s_prt[p_] = q_;
                                s_rotA[q_] = c;  s_rotB[q_] = sn;  s_prt[q_] = p_;
                            }
                            __syncthreads();
                            float ng[4], nu[4];
#pragma unroll
                            for (int e4 = 0; e4 < 4; ++e4) {
                                int e   = tid + e4 * 1024;
                                int row = e >> 6, col = e & 63;
                                int pr = s_prt[row], pc = s_prt[col];
                                float ar = s_rotA[row], br = s_rotB[row];
                                float ac = s_rotA[col], bc = s_rotB[col];
                                ng[e4] = ar * ac * s_G[cur][row * 64 + col]
                                       + br * ac * s_G[cur][pr * 64 + col]
                                       + ar * bc * s_G[cur][row * 64 + pc]
                                       + br * bc * s_G[cur][pr * 64 + pc];
                                nu[e4] = ac * s_U[cur][row * 64 + col]
                                       + bc * s_U[cur][row * 64 + pc];
                            }
#pragma unroll
                            for (int e4 = 0; e4 < 4; ++e4) {
                                int e = tid + e4 * 1024;
                                s_G[cur ^ 1][e] = ng[e4];
                                s_U[cur ^ 1][e] = nu[e4];
                            }
                            __syncthreads();
                            cur ^= 1;
                        }
                    }

                    // S3: eigenvalues, threshold, sort descending (stable rank)
                    if (tid < 64) {
                        float lam = s_G[cur][tid * 64 + tid];
                        if (lam <= THRES_F) lam = 0.f;
                        s_S[tid] = lam;
                    }
                    __syncthreads();
                    if (tid < 64) {
                        float my = s_S[tid];
                        int rank = 0;
                        for (int i = 0; i < 64; ++i) {
                            float o = s_S[i];
                            rank += ((o > my) || (o == my && i < tid)) ? 1 : 0;
                        }
                        s_perm[rank] = tid;
                        s_Ss[rank]   = my;
                    }
                    __syncthreads();
                    if (tid == 0) {
                        int nz = 0;
                        for (int i = 0; i < 64; ++i) nz += (s_Ss[i] > 0.f) ? 1 : 0;
                        s_misc[0] = nz;
                        s_misc[1] = (nz >= MM) ? 1 : 0;
                    }
                    __syncthreads();
                    const int   nnz = s_misc[0];
                    const int   ge  = s_misc[1];
                    const float S32 = s_Ss[MM];

                    // S4: Ueff[k][jn] = U[k][perm[jn]] * net_scale(jn)   (into s_G[0])
#pragma unroll
                    for (int e4 = 0; e4 < 4; ++e4) {
                        int e = tid + e4 * 1024;
                        int kk = e >> 6, jn = e & 63;
                        float Sj = s_Ss[jn];
                        float f;
                        if (ge) f = (jn < MM - 1 && Sj > 0.f)
                                      ? sqrtf(fmaxf(Sj - S32, 0.f) / Sj) : 0.f;
                        else    f = (jn < nnz) ? 1.f : 0.f;
                        s_G[0][kk * 64 + jn] = s_U[cur][kk * 64 + s_perm[jn]] * f;
                    }
                    __syncthreads();

                    // S5: remix B <- B * Ueff, tile by tile (old rows staged to LDS first)
#pragma unroll
                    for (int T = 0; T < 4; ++T) {
                        __syncthreads();
#pragma unroll
                        for (int mm = 0; mm < 4; ++mm) {
                            int rl = 4 * s + 64 * mm;
                            const float4 v = bf4[4 * T + mm];
                            TILE(rl + 0, j) = v.x; TILE(rl + 1, j) = v.y;
                            TILE(rl + 2, j) = v.z; TILE(rl + 3, j) = v.w;
                        }
                        __syncthreads();
#pragma unroll
                        for (int mm = 0; mm < 4; ++mm) {
                            int rl = 4 * s + 64 * mm;
                            float n0 = 0.f, n1 = 0.f, n2 = 0.f, n3 = 0.f;
                            for (int kk = 0; kk < 64; ++kk) {
                                float u = s_G[0][kk * 64 + j];
                                n0 += TILE(rl + 0, kk) * u;
                                n1 += TILE(rl + 1, kk) * u;
                                n2 += TILE(rl + 2, kk) * u;
                                n3 += TILE(rl + 3, kk) * u;
                            }
                            bf4[4 * T + mm] = make_float4(n0, n1, n2, n3);
                        }
                    }
                    rc = ge ? (MM - 1) : nnz;
                    // =============== end SHRINK ===============
                    shrunk = true;
                    t = t + k + 1;   // restart batching after the shrink step
                    break;
                }
                // in-batch additive corrections, PARALLEL over k2 (wave wv owns k2 = k+1+wv):
                // scalar_{k2} += (kap * (a_k . a_k2))^2 ; one barrier total per update
                for (int k2 = k + 1 + wv; k2 < bsz; k2 += 16) {
                    const float4* pa = (const float4*)(s_big + k  * 1024);
                    const float4* pb = (const float4*)(s_big + k2 * 1024);
                    float prod = 0.f;
#pragma unroll
                    for (int it = 0; it < 4; ++it) {
                        float4 x = pa[ln + 64 * it];
                        float4 y = pb[ln + 64 * it];
                        prod += x.x * y.x + x.y * y.y + x.z * y.z + x.w * y.w;
                    }
                    prod += __shfl_xor(prod, 1);  prod += __shfl_xor(prod, 2);
                    prod += __shfl_xor(prod, 4);  prod += __shfl_xor(prod, 8);
                    prod += __shfl_xor(prod, 16); prod += __shfl_xor(prod, 32);
                    if (ln == 0) {
                        float g = kap * prod;
                        s_corr[k2] += g * g;
                    }
                }
                __syncthreads();
            }
        }
        if (!shrunk) t += bsz;
    }
}

extern "C" void kernel_launch(void* const* d_in, const int* in_sizes, int n_in,
                              void* d_out, int out_size, void* d_ws, size_t ws_size,
                              hipStream_t stream) {
    (void)in_sizes; (void)n_in; (void)d_ws; (void)ws_size; (void)out_size;
    const float* A = (const float*)d_in[0];   // inputs_matrix [20000,1024] f32
    const float* Y = (const float*)d_in[1];   // outputs [20000] f32
    float* out = (float*)d_out;               // preds [20000] f32
    SFTRL_CCFM_kernel<<<dim3(1), dim3(1024), 0, stream>>>(A, Y, out);
}

// Round 3
// 4191.696 us; speedup vs baseline: 60.1368x; 5.2927x over previous
//
#include <hip/hip_runtime.h>
#include <hip/hip_cooperative_groups.h>
#include <math.h>

namespace cg = cooperative_groups;

#define NDATA   20000
#define DFEAT   1024
#define TWO_M   64
#define MM      32
#define ETA_F   1e-4f
#define THRES_F 1e-12f
#define NSWEEP  10
#define NBLK    128
#define NTHR    1024

// d_ws layout:
//   ctl[0..3] : int  t* slots (ring of 4)
//   ctl[4]    : int  rc after shrink
//   Bt at byte offset 256: float[TWO_M * DFEAT]  (row j = column j of B, contiguous)

__device__ __forceinline__ float wave_reduce(float v) {
    v += __shfl_xor(v, 1);  v += __shfl_xor(v, 2);  v += __shfl_xor(v, 4);
    v += __shfl_xor(v, 8);  v += __shfl_xor(v, 16); v += __shfl_xor(v, 32);
    return v;
}

__device__ __forceinline__ void pair_from(int p, int &a, int &b) {
    // p in [0, 2080) -> (a,b), a<=b, over 64x64 upper triangle
    int a_ = 0, rem = p;
    while (rem >= 64 - a_) { rem -= 64 - a_; ++a_; }
    a = a_; b = a_ + rem;
}

__global__ __launch_bounds__(NTHR, 4)
void sftrl_coop(const float* __restrict__ A,   // [20000][1024]
                const float* __restrict__ Y,   // [20000]
                float* __restrict__ out,       // [20000] scalars (final outputs)
                int* __restrict__ ctl,         // control ints in ws
                float* __restrict__ Bt)        // [64][1024] B transposed, in ws
{
    cg::grid_group grid = cg::this_grid();
    const int tid   = threadIdx.x;
    const int lane  = tid & 63;
    const int gwave = blockIdx.x * (NTHR / 64) + (tid >> 6);
    const int nwaves = gridDim.x * (NTHR / 64);
    const bool blk0 = (blockIdx.x == 0);

    // LDS: only used by block 0 during (rare) shrink
    __shared__ float tg[64 * 257];        // 64 rows x 256-dim chunk, pad 257
    __shared__ float s_G[2][4096];
    __shared__ float s_U[2][4096];
    __shared__ float s_rotA[64], s_rotB[64];
    __shared__ int   s_prt[64];
    __shared__ float s_S[64], s_Ss[64];
    __shared__ int   s_perm[64];
    __shared__ int   s_misc[2];

    // ---- init (every call: out/ws are poisoned) ----
    for (int i = blockIdx.x * NTHR + tid; i < NDATA; i += gridDim.x * NTHR) out[i] = 0.f;
    for (int i = blockIdx.x * NTHR + tid; i < TWO_M * DFEAT; i += gridDim.x * NTHR) Bt[i] = 0.f;
    if (blk0 && tid < 4) ctl[tid] = NDATA;
    __threadfence();
    grid.sync();

    int   p = 0;          // ring slot index
    int   rc = 0;
    int   mode = 0;       // 0 = initial scan, 1 = rank-1 correct+scan, 2 = full recompute+scan
    int   tstar = -1;
    float kap = 0.f;

    for (;;) {
        // ================= fused pass: correct scalars (if needed) + scan for next trigger =====
        if (mode == 0) {
            for (int tq = blockIdx.x * NTHR + tid; tq < NDATA; tq += gridDim.x * NTHR) {
                if (0.f <= Y[tq]) atomicMin(&ctl[p], tq);
            }
        } else if (mode == 1) {
            // cache alpha_{t*} slice (16 dims per lane)
            const float4* Ast = (const float4*)(A + (size_t)tstar * DFEAT);
            float4 as0 = Ast[lane * 4 + 0], as1 = Ast[lane * 4 + 1];
            float4 as2 = Ast[lane * 4 + 2], as3 = Ast[lane * 4 + 3];
            for (int tq = tstar + 1 + gwave; tq < NDATA; tq += nwaves) {
                const float4* At = (const float4*)(A + (size_t)tq * DFEAT);
                float4 a0 = At[lane * 4 + 0], a1 = At[lane * 4 + 1];
                float4 a2 = At[lane * 4 + 2], a3 = At[lane * 4 + 3];
                float d = as0.x * a0.x + as0.y * a0.y + as0.z * a0.z + as0.w * a0.w;
                d += as1.x * a1.x + as1.y * a1.y + as1.z * a1.z + as1.w * a1.w;
                d += as2.x * a2.x + as2.y * a2.y + as2.z * a2.z + as2.w * a2.w;
                d += as3.x * a3.x + as3.y * a3.y + as3.z * a3.z + as3.w * a3.w;
                d = wave_reduce(d);
                float v  = kap * d;
                float sc = out[tq] + v * v;
                if (lane == 0) {
                    out[tq] = sc;
                    if (sc <= Y[tq]) atomicMin(&ctl[p], tq);
                }
            }
        } else {
            // full recompute: sc = ||B^T alpha_t||^2 (after shrink)
            for (int tq = tstar + 1 + gwave; tq < NDATA; tq += nwaves) {
                const float4* At = (const float4*)(A + (size_t)tq * DFEAT);
                float4 a0 = At[lane * 4 + 0], a1 = At[lane * 4 + 1];
                float4 a2 = At[lane * 4 + 2], a3 = At[lane * 4 + 3];
                float sc = 0.f;
                for (int jc = 0; jc < TWO_M; ++jc) {
                    const float4* Bj = (const float4*)(Bt + (size_t)jc * DFEAT);
                    float4 b0 = Bj[lane * 4 + 0], b1 = Bj[lane * 4 + 1];
                    float4 b2 = Bj[lane * 4 + 2], b3 = Bj[lane * 4 + 3];
                    float d = a0.x * b0.x + a0.y * b0.y + a0.z * b0.z + a0.w * b0.w;
                    d += a1.x * b1.x + a1.y * b1.y + a1.z * b1.z + a1.w * b1.w;
                    d += a2.x * b2.x + a2.y * b2.y + a2.z * b2.z + a2.w * b2.w;
                    d += a3.x * b3.x + a3.y * b3.y + a3.z * b3.z + a3.w * b3.w;
                    d = wave_reduce(d);
                    sc += d * d;
                }
                if (lane == 0) {
                    out[tq] = sc;
                    if (sc <= Y[tq]) atomicMin(&ctl[p], tq);
                }
            }
        }
        // reset the ring slot two ahead (last read >=1 full grid-sync ago)
        if (blk0 && tid == 0) ctl[(p + 2) & 3] = NDATA;
        __threadfence();
        grid.sync();                                   // ---- SYNC A ----

        int ts = ctl[p];
        p = (p + 1) & 3;
        if (ts >= NDATA) break;                        // no more triggers: done

        float scst = out[ts];
        float bst  = Y[ts];
        kap = sqrtf(2.f * ETA_F * (bst - scst));
        rc += 1;

        if (blk0) {                                    // append column rc: Bt[rc][:] = kap*alpha
            Bt[(size_t)rc * DFEAT + tid] = kap * A[(size_t)ts * DFEAT + tid];
        }

        if (rc == TWO_M - 1) {
            // ======================= SHRINK (block 0 only) =======================
            if (blk0) {
                __syncthreads();                       // column write visible in-block
                // S1: Gram G = Bt * Bt^T via 4 chunks of 256 dims staged in LDS
                float acc0 = 0.f, acc1 = 0.f, acc2 = 0.f;
                int a0i, b0i, a1i, b1i, a2i, b2i;
                pair_from(tid, a0i, b0i);
                pair_from(tid + 1024, a1i, b1i);
                pair_from((tid < 32) ? (tid + 2048) : 0, a2i, b2i);
                for (int c = 0; c < 4; ++c) {
                    __syncthreads();
                    for (int q = tid; q < 64 * 64; q += NTHR) {      // 4096 float4 stages
                        int jj = q >> 6, d4 = q & 63;
                        float4 v = ((const float4*)(Bt + (size_t)jj * DFEAT + c * 256))[d4];
                        tg[jj * 257 + d4 * 4 + 0] = v.x;
                        tg[jj * 257 + d4 * 4 + 1] = v.y;
                        tg[jj * 257 + d4 * 4 + 2] = v.z;
                        tg[jj * 257 + d4 * 4 + 3] = v.w;
                    }
                    __syncthreads();
                    for (int dd = 0; dd < 256; ++dd) {
                        acc0 += tg[a0i * 257 + dd] * tg[b0i * 257 + dd];
                        acc1 += tg[a1i * 257 + dd] * tg[b1i * 257 + dd];
                        acc2 += tg[a2i * 257 + dd] * tg[b2i * 257 + dd];
                    }
                }
                s_G[0][a0i * 64 + b0i] = acc0; s_G[0][b0i * 64 + a0i] = acc0;
                s_G[0][a1i * 64 + b1i] = acc1; s_G[0][b1i * 64 + a1i] = acc1;
                if (tid < 32) { s_G[0][a2i * 64 + b2i] = acc2; s_G[0][b2i * 64 + a2i] = acc2; }
                for (int e4 = 0; e4 < 4; ++e4) {
                    int e = tid + e4 * 1024;
                    s_U[0][e] = ((e >> 6) == (e & 63)) ? 1.f : 0.f;
                }
                __syncthreads();

                // S2: tournament-cyclic Jacobi
                int cur = 0;
                for (int sw = 0; sw < NSWEEP; ++sw) {
                    for (int r = 0; r < 63; ++r) {
                        if (tid < 32) {
                            int p_, q_;
                            if (tid == 0) { p_ = 63; q_ = r; }
                            else { p_ = (r + tid) % 63; q_ = (r + 63 - tid) % 63; }
                            float gpp = s_G[cur][p_ * 64 + p_];
                            float gqq = s_G[cur][q_ * 64 + q_];
                            float gpq = s_G[cur][p_ * 64 + q_];
                            float cc = 1.f, sn = 0.f;
                            if (fabsf(gpq) > 1e-20f) {
                                float tau = (gqq - gpp) / (2.f * gpq);
                                float tt  = (tau >= 0.f ? 1.f : -1.f) /
                                            (fabsf(tau) + sqrtf(1.f + tau * tau));
                                cc = 1.f / sqrtf(1.f + tt * tt);
                                sn = tt * cc;
                            }
                            s_rotA[p_] = cc; s_rotB[p_] = -sn; s_prt[p_] = q_;
                            s_rotA[q_] = cc; s_rotB[q_] = sn;  s_prt[q_] = p_;
                        }
                        __syncthreads();
                        float ng[4], nu[4];
                        for (int e4 = 0; e4 < 4; ++e4) {
                            int e = tid + e4 * 1024;
                            int row = e >> 6, col = e & 63;
                            int pr = s_prt[row], pc = s_prt[col];
                            float ar = s_rotA[row], br = s_rotB[row];
                            float ac = s_rotA[col], bc = s_rotB[col];
                            ng[e4] = ar * ac * s_G[cur][row * 64 + col]
                                   + br * ac * s_G[cur][pr * 64 + col]
                                   + ar * bc * s_G[cur][row * 64 + pc]
                                   + br * bc * s_G[cur][pr * 64 + pc];
                            nu[e4] = ac * s_U[cur][row * 64 + col]
                                   + bc * s_U[cur][row * 64 + pc];
                        }
                        for (int e4 = 0; e4 < 4; ++e4) {
                            int e = tid + e4 * 1024;
                            s_G[cur ^ 1][e] = ng[e4];
                            s_U[cur ^ 1][e] = nu[e4];
                        }
                        __syncthreads();
                        cur ^= 1;
                    }
                }

                // S3: eigenvalues, threshold, sort descending (stable)
                if (tid < 64) {
                    float lam = s_G[cur][tid * 64 + tid];
                    if (lam <= THRES_F) lam = 0.f;
                    s_S[tid] = lam;
                }
                __syncthreads();
                if (tid < 64) {
                    float my = s_S[tid];
                    int rank = 0;
                    for (int i = 0; i < 64; ++i) {
                        float o = s_S[i];
                        rank += ((o > my) || (o == my && i < tid)) ? 1 : 0;
                    }
                    s_perm[rank] = tid;
                    s_Ss[rank]   = my;
                }
                __syncthreads();
                if (tid == 0) {
                    int nz = 0;
                    for (int i = 0; i < 64; ++i) nz += (s_Ss[i] > 0.f) ? 1 : 0;
                    s_misc[0] = nz;
                    s_misc[1] = (nz >= MM) ? 1 : 0;
                }
                __syncthreads();
                const int   nnz = s_misc[0];
                const int   ge  = s_misc[1];
                const float S32 = s_Ss[MM];

                // S4: Ueff[k][jn] = U[k][perm[jn]] * net_scale(jn)  -> s_G[0]
                for (int e4 = 0; e4 < 4; ++e4) {
                    int e = tid + e4 * 1024;
                    int kk = e >> 6, jn = e & 63;
                    float Sj = s_Ss[jn];
                    float f;
                    if (ge) f = (jn < MM - 1 && Sj > 0.f)
                                  ? sqrtf(fmaxf(Sj - S32, 0.f) / Sj) : 0.f;
                    else    f = (jn < nnz) ? 1.f : 0.f;
                    s_G[0][kk * 64 + jn] = s_U[cur][kk * 64 + s_perm[jn]] * f;
                }
                __syncthreads();

                // S5: Bt_new[jn][:] = sum_k Ueff[k][jn] * Bt_old[k][:]  (chunked, in-place)
                for (int c = 0; c < 4; ++c) {
                    __syncthreads();
                    for (int q = tid; q < 64 * 64; q += NTHR) {
                        int jj = q >> 6, d4 = q & 63;
                        float4 v = ((const float4*)(Bt + (size_t)jj * DFEAT + c * 256))[d4];
                        tg[jj * 257 + d4 * 4 + 0] = v.x;
                        tg[jj * 257 + d4 * 4 + 1] = v.y;
                        tg[jj * 257 + d4 * 4 + 2] = v.z;
                        tg[jj * 257 + d4 * 4 + 3] = v.w;
                    }
                    __syncthreads();
                    for (int q = tid; q < 64 * 256; q += NTHR) {
                        int dd = q & 255, jn = q >> 8;
                        float sum = 0.f;
                        for (int kk = 0; kk < 64; ++kk)
                            sum += tg[kk * 257 + dd] * s_G[0][kk * 64 + jn];
                        Bt[(size_t)jn * DFEAT + c * 256 + dd] = sum;
                    }
                }
                __syncthreads();
                if (tid == 0) {
                    ctl[4] = ge ? (MM - 1) : nnz;
                    __threadfence();
                }
            }
            grid.sync();                               // ---- SYNC B ----
            rc = ctl[4];
            mode = 2;                                  // full recompute next pass
        } else {
            mode = 1;                                  // rank-1 correction next pass
        }
        tstar = ts;
    }
}

extern "C" void kernel_launch(void* const* d_in, const int* in_sizes, int n_in,
                              void* d_out, int out_size, void* d_ws, size_t ws_size,
                              hipStream_t stream) {
    (void)in_sizes; (void)n_in; (void)ws_size; (void)out_size;
    const float* A  = (const float*)d_in[0];   // [20000,1024] f32
    const float* Y  = (const float*)d_in[1];   // [20000] f32
    float* out      = (float*)d_out;
    int*   ctl      = (int*)d_ws;
    float* Bt       = (float*)((char*)d_ws + 256);

    void* kargs[] = { (void*)&A, (void*)&Y, (void*)&out, (void*)&ctl, (void*)&Bt };
    hipLaunchCooperativeKernel((void*)sftrl_coop, dim3(NBLK), dim3(NTHR),
                               kargs, 0, stream);
}